// Round 11
// baseline (45.403 us; speedup 1.0000x reference)
//
#include <hip/hip_runtime.h>
#include <math.h>
#include <stdint.h>

#define DIM  4096
#define KOUT 10
#define BATCH 4096

typedef float float2v __attribute__((ext_vector_type(2)));

// XOR-swizzle on linear LDS float index (verified R1/R4/R6/R8):
// XOR row bits (6-8) into 16B-granule slot bits (2-4). Involution.
__device__ __forceinline__ int swzAddr(int lin) {
    return lin ^ (((lin >> 6) & 7) << 2);
}

__device__ __forceinline__ float rlane(float v, int lane) {
    return __int_as_float(__builtin_amdgcn_readlane(__float_as_int(v), lane));
}

// ---- in-register lifting layers on 8 float2v (16 scalars) ----
// t = tan(phi/2), s = sin(phi) (or -cot/-sin => -R; sign cancels in probs).
__device__ __forceinline__ void liftIntra8(float2v* h, float t, float s) {
#pragma unroll
    for (int m = 0; m < 8; ++m) {
        float a = h[m].x, b = h[m].y;
        float a1 = fmaf(-t, b, a);
        float b1 = fmaf(s, a1, b);
        h[m].x = fmaf(-t, b1, a1);
        h[m].y = b1;
    }
}
template<int KP>   // reg-index bit KP (scalar state bit KP+1), KP in 0..2
__device__ __forceinline__ void liftPk8(float2v* h, float t, float s) {
    const float2v tv = { -t, -t }, sv = { s, s };
#pragma unroll
    for (int m = 0; m < 4; ++m) {
        const int i0 = ((m >> KP) << (KP + 1)) | (m & ((1 << KP) - 1));
        const int i1 = i0 | (1 << KP);
        float2v a = h[i0], b = h[i1];
        float2v a1 = __builtin_elementwise_fma(tv, b, a);
        float2v b1 = __builtin_elementwise_fma(sv, a1, b);
        h[i1] = b1;
        h[i0] = __builtin_elementwise_fma(tv, b1, a1);
    }
}

// Cross-lane RY layer on lane-bit B (true rotation; c=cos(phi), s=sin(phi)).
// Pair (bit=0 value A, bit=1 value B_): A' = c*A - s*B_ ; B_' = s*A + c*B_.
// Per lane: r_new = c*r + sgn*s*partner, sgn = +1 if (l&B) else -1.
template<int B>
__device__ __forceinline__ void liftShfl(float2v* h, float c, float s, int l) {
    const float ssg = (l & B) ? s : -s;
    const float2v cv = { c, c }, sv = { ssg, ssg };
#pragma unroll
    for (int m = 0; m < 8; ++m) {
        float2v p;
        p.x = __shfl_xor(h[m].x, B, 64);
        p.y = __shfl_xor(h[m].y, B, 64);
        float2v cr = h[m] * cv;
        h[m] = __builtin_elementwise_fma(sv, p, cr);
    }
}

// Layout P: d = l*64 + w*16 + u  (u0=comp, u1-3=reg idx; w bits = q4,q5; l bits = q6-11)
// Layout Q: d = (w*16 + u)*64 + l  (l bits = q0-5; u0=comp=q6, u1-3=q7-9; w bits = q10,q11)
__global__ __launch_bounds__(256, 8) void vqc_kernel(
        const float* __restrict__ x,
        const float* __restrict__ theta,
        float* __restrict__ out)
{
    __shared__ __align__(16) float lds[DIM];    // 16 KB, full transpose buffer
    __shared__ float red[4][16];                // cross-wave reduction staging
    const int tid = threadIdx.x;
    const int l = tid & 63, w = tid >> 6;
    const int b = blockIdx.x;

    // Gate params. RY(theta) rotates by phi = theta/2. Lifting: t=tan(theta/4),
    // s=sin(theta/2) (alt -cot/-sin keeps |t|<=1). Shfl layers use true (c,s).
    float th = theta[l < 24 ? l : 0];
    float qh = 0.25f * th;
    float sq = sinf(qh), cq = cosf(qh);
    float sfull = 2.f * sq * cq;                    // sin(theta/2)
    float cfull = fmaf(-2.f * sq, sq, 1.f);         // cos(theta/2)
    float tt, ss;
    if (fabsf(sq) <= fabsf(cq)) { tt = sq / cq;  ss = sfull;  }
    else                        { tt = -cq / sq; ss = -sfull; }

    // ---- load layout P: r[u] = x[b*DIM + l*64 + w*16 + u], 4 b128/lane ----
    float2v r2[8];
    const float4* x4 = reinterpret_cast<const float4*>(x + (size_t)b * DIM + l * 64 + w * 16);
#pragma unroll
    for (int e = 0; e < 4; ++e) {
        const float4 v = x4[e];
        float2v lo; lo.x = v.x; lo.y = v.y;
        float2v hi; hi.x = v.z; hi.y = v.w;
        r2[2 * e] = lo; r2[2 * e + 1] = hi;
    }

    // ---- layer 1 in P: q0-3 in-reg; q10,q11 cross-lane (l bits 4,5) ----
    liftIntra8(r2, rlane(tt, 0), rlane(ss, 0));
    liftPk8<0>(r2, rlane(tt, 1), rlane(ss, 1));
    liftPk8<1>(r2, rlane(tt, 2), rlane(ss, 2));
    liftPk8<2>(r2, rlane(tt, 3), rlane(ss, 3));
    liftShfl<16>(r2, rlane(cfull, 10), rlane(sfull, 10), l);
    liftShfl<32>(r2, rlane(cfull, 11), rlane(sfull, 11), l);

    // ---- transpose P -> Q (write-all, barrier, read-all, barrier) ----
#pragma unroll
    for (int e = 0; e < 4; ++e)
        *reinterpret_cast<float4*>(&lds[swzAddr(l * 64 + w * 16 + 4 * e)]) =
            make_float4(r2[2 * e].x, r2[2 * e].y, r2[2 * e + 1].x, r2[2 * e + 1].y);
    __syncthreads();
#pragma unroll
    for (int m = 0; m < 8; ++m) {
        float2v nv;
        nv.x = lds[swzAddr((w * 16 + 2 * m) * 64 + l)];
        nv.y = lds[swzAddr((w * 16 + 2 * m + 1) * 64 + l)];
        r2[m] = nv;
    }
    __syncthreads();   // WAR: all reads done before transpose-2's writes

    // ---- layer 1 in Q: q4,q5 cross-lane (l bits 4,5); q6-9 in-reg ----
    liftShfl<16>(r2, rlane(cfull, 4), rlane(sfull, 4), l);
    liftShfl<32>(r2, rlane(cfull, 5), rlane(sfull, 5), l);
    liftIntra8(r2, rlane(tt, 6), rlane(ss, 6));
    liftPk8<0>(r2, rlane(tt, 7), rlane(ss, 7));
    liftPk8<1>(r2, rlane(tt, 8), rlane(ss, 8));
    liftPk8<2>(r2, rlane(tt, 9), rlane(ss, 9));

    // ---- CZ diagonal in Q. d bits: q0-5=l, q6=comp, q7-9=reg idx, q10=w0, q11=w1.
    // flip = f(l) ^ (u0&l5) ^ g(u) ^ (u3&w0) ^ (w0&w1) ^ (l0&w1)
    // verified on d = 4095, 96, 1536, 2049, 48.
    {
        const int fl = __popc(l & (l >> 1) & 0x1F) & 1;
        const int l0 = l & 1, l5 = (l >> 5) & 1;
        const int w0 = w & 1, w1 = (w >> 1) & 1;
        const int base = fl ^ (w0 & w1) ^ (l0 & w1);
        uint32_t M[4];                      // idx = u0 | (u3<<1)
        M[0] = (uint32_t)(base)           << 31;
        M[1] = (uint32_t)(base ^ l5)      << 31;
        M[2] = (uint32_t)(base ^ w0)      << 31;
        M[3] = (uint32_t)(base ^ l5 ^ w0) << 31;
#pragma unroll
        for (int m = 0; m < 8; ++m) {
            const int m0 = m & 1, m1 = (m >> 1) & 1, m2 = (m >> 2) & 1;
            const int gx = (m0 & m1) ^ (m1 & m2);        // g(u), comp=0
            const int gy = m0 ^ gx;                      // g(u), comp=1
            const uint32_t mx = M[(0) | (m2 << 1)] ^ ((uint32_t)gx << 31);
            const uint32_t my = M[(1) | (m2 << 1)] ^ ((uint32_t)gy << 31);
            r2[m].x = __uint_as_float(__float_as_uint(r2[m].x) ^ mx);
            r2[m].y = __uint_as_float(__float_as_uint(r2[m].y) ^ my);
        }
    }

    // ---- layer 2 in Q: q6-9 in-reg (theta[18..21]); q4,q5 (theta[16,17]) ----
    liftIntra8(r2, rlane(tt, 18), rlane(ss, 18));
    liftPk8<0>(r2, rlane(tt, 19), rlane(ss, 19));
    liftPk8<1>(r2, rlane(tt, 20), rlane(ss, 20));
    liftPk8<2>(r2, rlane(tt, 21), rlane(ss, 21));
    liftShfl<16>(r2, rlane(cfull, 16), rlane(sfull, 16), l);
    liftShfl<32>(r2, rlane(cfull, 17), rlane(sfull, 17), l);

    // ---- transpose Q -> P ----
#pragma unroll
    for (int m = 0; m < 8; ++m) {
        lds[swzAddr((w * 16 + 2 * m) * 64 + l)]     = r2[m].x;
        lds[swzAddr((w * 16 + 2 * m + 1) * 64 + l)] = r2[m].y;
    }
    __syncthreads();
#pragma unroll
    for (int e = 0; e < 4; ++e) {
        const float4 v = *reinterpret_cast<const float4*>(&lds[swzAddr(l * 64 + w * 16 + 4 * e)]);
        float2v lo; lo.x = v.x; lo.y = v.y;
        float2v hi; hi.x = v.z; hi.y = v.w;
        r2[2 * e] = lo; r2[2 * e + 1] = hi;
    }
    // lds not reused after this point; red is a separate buffer.

    // ---- layer 2 in P: q0-3 (theta[12..15]); q10,q11 (theta[22,23]) ----
    liftIntra8(r2, rlane(tt, 12), rlane(ss, 12));
    liftPk8<0>(r2, rlane(tt, 13), rlane(ss, 13));
    liftPk8<1>(r2, rlane(tt, 14), rlane(ss, 14));
    liftPk8<2>(r2, rlane(tt, 15), rlane(ss, 15));
    liftShfl<16>(r2, rlane(cfull, 22), rlane(sfull, 22), l);
    liftShfl<32>(r2, rlane(cfull, 23), rlane(sfull, 23), l);

    // ---- measurement in P: q0=comp, q1-3=reg bits, q4=w0, q5=w1, q6-9=l0-3 ----
#pragma unroll
    for (int m = 0; m < 8; ++m) r2[m] *= r2[m];
    float v0 = 0.f, v1 = 0.f, v2 = 0.f;
    float q16s[8];
#pragma unroll
    for (int m = 0; m < 8; ++m) { v0 += r2[m].y; q16s[m] = r2[m].x + r2[m].y; }
    float q8s[4];
#pragma unroll
    for (int m = 0; m < 4; ++m) { v1 += q16s[2*m+1]; q8s[m] = q16s[2*m] + q16s[2*m+1]; }
    float q4s[2];
#pragma unroll
    for (int m = 0; m < 2; ++m) { v2 += q8s[2*m+1]; q4s[m] = q8s[2*m] + q8s[2*m+1]; }
    const float v3   = q4s[1];
    const float psum = q4s[0] + q4s[1];

    float vv[10];
    vv[0] = v0; vv[1] = v1; vv[2] = v2; vv[3] = v3;
    vv[4] = (w & 1) ? psum : 0.f;
    vv[5] = (w & 2) ? psum : 0.f;
    vv[6] = (l & 1) ? psum : 0.f;
    vv[7] = (l & 2) ? psum : 0.f;
    vv[8] = (l & 4) ? psum : 0.f;
    vv[9] = (l & 8) ? psum : 0.f;

#pragma unroll
    for (int k = 0; k < KOUT; ++k) {
        float t = vv[k];
#pragma unroll
        for (int off = 32; off >= 1; off >>= 1)
            t += __shfl_xor(t, off, 64);
        vv[k] = t;
    }

    if (l == 0) {
#pragma unroll
        for (int k = 0; k < KOUT; ++k) red[w][k] = vv[k];
    }
    __syncthreads();
    if (w == 0 && l < KOUT)
        out[b * KOUT + l] = red[0][l] + red[1][l] + red[2][l] + red[3][l];
}

extern "C" void kernel_launch(void* const* d_in, const int* in_sizes, int n_in,
                              void* d_out, int out_size, void* d_ws, size_t ws_size,
                              hipStream_t stream) {
    const float* x     = (const float*)d_in[0];
    const float* theta = (const float*)d_in[1];
    float* out         = (float*)d_out;
    vqc_kernel<<<BATCH, 256, 0, stream>>>(x, theta, out);
}

// Round 13
// 25.555 us; speedup vs baseline: 1.7766x; 1.7766x over previous
//
#include <hip/hip_runtime.h>
#include <math.h>
#include <stdint.h>

#define DIM  4096
#define KOUT 10
#define BATCH 4096

typedef float float2v __attribute__((ext_vector_type(2)));

// XOR-swizzle on linear LDS float index (verified R1/R4/R6/R8).
__device__ __forceinline__ int swzAddr(int lin) {
    return lin ^ (((lin >> 6) & 7) << 2);
}

__device__ __forceinline__ float rlane(float v, int lane) {
    return __int_as_float(__builtin_amdgcn_readlane(__float_as_int(v), lane));
}

// Drain all pending LDS ops (necessity verified R6): protects the
// phase-0-read -> phase-1-write WAR inside the time-shared transpose.
__device__ __forceinline__ void ldsFence() {
    __builtin_amdgcn_sched_barrier(0);
    asm volatile("s_waitcnt lgkmcnt(0)" ::: "memory");
    __builtin_amdgcn_sched_barrier(0);
}

// Canonical GCN wave64 sum via DPP (VALU-only, no DS pipe). gfx9 DPP hazard:
// a VALU write followed by a DPP read of that VGPR needs 2 wait states, and
// the compiler does NOT insert them inside/around inline asm -> explicit
// s_nop 1 before every DPP op (including the entry, vs compiler VALU).
// After row_shr 1/2/4/8: lane15 of each 16-row holds the row sum.
// row_bcast:15 adds row r's lane15 into row r+1; row_bcast:31 adds lane31
// (=S0+S1) into rows 2,3. Lane 63 = S3+S2+(S0+S1) = full total.
__device__ __forceinline__ float dppSum64(float v) {
    asm volatile(
        "s_nop 1\n\t"
        "v_add_f32_dpp %0, %0, %0 row_shr:1  row_mask:0xf bank_mask:0xf bound_ctrl:0\n\t"
        "s_nop 1\n\t"
        "v_add_f32_dpp %0, %0, %0 row_shr:2  row_mask:0xf bank_mask:0xf bound_ctrl:0\n\t"
        "s_nop 1\n\t"
        "v_add_f32_dpp %0, %0, %0 row_shr:4  row_mask:0xf bank_mask:0xf bound_ctrl:0\n\t"
        "s_nop 1\n\t"
        "v_add_f32_dpp %0, %0, %0 row_shr:8  row_mask:0xf bank_mask:0xf bound_ctrl:0\n\t"
        "s_nop 1\n\t"
        "v_add_f32_dpp %0, %0, %0 row_bcast:15 row_mask:0xf bank_mask:0xf bound_ctrl:0\n\t"
        "s_nop 1\n\t"
        "v_add_f32_dpp %0, %0, %0 row_bcast:31 row_mask:0xf bank_mask:0xf bound_ctrl:0\n\t"
        : "+v"(v));
    return v;   // lane 63 = total
}

// Packed RY lifting layer on scalar state bit KP+1 (verified R8).
// t = tan(phi/2), s = sin(phi) (or -cot/-sin => -R; sign cancels in probs).
template<int KP>
__device__ __forceinline__ void liftPk(float2v r2[32], float t, float s) {
    const float2v tv = { -t, -t };
    const float2v sv = {  s,  s };
#pragma unroll
    for (int m = 0; m < 16; ++m) {
        const int i0 = ((m >> KP) << (KP + 1)) | (m & ((1 << KP) - 1));
        const int i1 = i0 | (1 << KP);
        float2v a = r2[i0], b = r2[i1];
        float2v a1 = __builtin_elementwise_fma(tv, b, a);
        float2v b1 = __builtin_elementwise_fma(sv, a1, b);
        r2[i1] = b1;
        r2[i0] = __builtin_elementwise_fma(tv, b1, a1);
    }
}

// Half-array variants (verified R10): state bits 1..4 stay within a half.
template<int KP>
__device__ __forceinline__ void liftPkH(float2v* h, float t, float s) {
    const float2v tv = { -t, -t };
    const float2v sv = {  s,  s };
#pragma unroll
    for (int m = 0; m < 8; ++m) {
        const int i0 = ((m >> KP) << (KP + 1)) | (m & ((1 << KP) - 1));
        const int i1 = i0 | (1 << KP);
        float2v a = h[i0], b = h[i1];
        float2v a1 = __builtin_elementwise_fma(tv, b, a);
        float2v b1 = __builtin_elementwise_fma(sv, a1, b);
        h[i1] = b1;
        h[i0] = __builtin_elementwise_fma(tv, b1, a1);
    }
}

__device__ __forceinline__ void liftIntraH(float2v* h, float t, float s) {
#pragma unroll
    for (int m = 0; m < 16; ++m) {
        float a = h[m].x, b = h[m].y;
        float a1 = fmaf(-t, b, a);
        float b1 = fmaf(s, a1, b);
        h[m].x = fmaf(-t, b1, a1);
        h[m].y = b1;
    }
}

// Full-array scalar layer on state bit 0 (verified R8).
__device__ __forceinline__ void liftIntra(float2v r2[32], float t, float s) {
#pragma unroll
    for (int m = 0; m < 32; ++m) {
        float a = r2[m].x, b = r2[m].y;
        float a1 = fmaf(-t, b, a);
        float b1 = fmaf(s, a1, b);
        r2[m].x = fmaf(-t, b1, a1);
        r2[m].y = b1;
    }
}

// 8 KB time-shared lane<->reg transpose, single middle fence (verified R10).
// Scalar semantics (verified R6/R8): r_new[j]@lane l = r_old[l]@lane j.
__device__ __forceinline__ void transpose64(float2v r2[32], float* lds, int l) {
    float tmp[32];
    if (l < 32) {
#pragma unroll
        for (int e4 = 0; e4 < 16; ++e4)
            *reinterpret_cast<float4*>(&lds[swzAddr(l * 64 + e4 * 4)]) =
                make_float4(r2[2 * e4].x, r2[2 * e4].y,
                            r2[2 * e4 + 1].x, r2[2 * e4 + 1].y);
    }
#pragma unroll
    for (int j = 0; j < 32; ++j)
        tmp[j] = lds[swzAddr(j * 64 + l)];          // new scalars 0..31
    ldsFence();                 // WAR: phase-0 reads must land before overwrite
    if (l >= 32) {
#pragma unroll
        for (int e4 = 0; e4 < 16; ++e4)
            *reinterpret_cast<float4*>(&lds[swzAddr((l - 32) * 64 + e4 * 4)]) =
                make_float4(r2[2 * e4].x, r2[2 * e4].y,
                            r2[2 * e4 + 1].x, r2[2 * e4 + 1].y);
    }
#pragma unroll
    for (int m = 0; m < 16; ++m) {                  // new scalars 32..63
        float2v w;
        w.x = lds[swzAddr((2 * m) * 64 + l)];
        w.y = lds[swzAddr((2 * m + 1) * 64 + l)];
        r2[16 + m] = w;
    }
#pragma unroll
    for (int m = 0; m < 16; ++m) {
        float2v w; w.x = tmp[2 * m]; w.y = tmp[2 * m + 1];
        r2[m] = w;
    }
}

__global__ __launch_bounds__(64) void vqc_kernel(
        const float* __restrict__ x,
        const float* __restrict__ theta,
        float* __restrict__ out)
{
    __shared__ __align__(16) float lds[2048];   // 8 KB
    const int l = threadIdx.x;   // one wave per block, one batch row per block
    const int b = blockIdx.x;

    // Gate params for lifting. RY(theta) rotates by phi = theta/2:
    // t = tan(theta/4), s = sin(theta/2); alt branch -R(phi) keeps |t|<=1.
    float th = theta[l < 24 ? l : 0];
    float qh = 0.25f * th;
    float sq = sinf(qh), cq = cosf(qh);
    float sfull = 2.f * sq * cq;                       // sin(theta/2)
    float tt, ss;
    if (fabsf(sq) <= fabsf(cq)) { tt = sq / cq;  ss = sfull;  }
    else                        { tt = -cq / sq; ss = -sfull; }

    // ---- issue all 16 global loads, then compute halves as data arrives ----
    float2v r2[32];
    const float4* x4 = reinterpret_cast<const float4*>(x + (size_t)b * DIM + l * 64);
#pragma unroll
    for (int e4 = 0; e4 < 16; ++e4) {
        const float4 w = x4[e4];
        float2v lo; lo.x = w.x; lo.y = w.y;
        float2v hi; hi.x = w.z; hi.y = w.w;
        r2[2 * e4]     = lo;
        r2[2 * e4 + 1] = hi;
    }

    // ---- pass 1: qubits 0-5, layer 1 (half-split for load overlap, R10) ----
    {
        const float t0 = rlane(tt, 0), s0 = rlane(ss, 0);
        const float t1 = rlane(tt, 1), s1 = rlane(ss, 1);
        const float t2 = rlane(tt, 2), s2 = rlane(ss, 2);
        const float t3 = rlane(tt, 3), s3 = rlane(ss, 3);
        const float t4 = rlane(tt, 4), s4 = rlane(ss, 4);
        liftIntraH (r2,      t0, s0);
        liftPkH<0>(r2,       t1, s1);
        liftPkH<1>(r2,       t2, s2);
        liftPkH<2>(r2,       t3, s3);
        liftPkH<3>(r2,       t4, s4);
        liftIntraH (r2 + 16, t0, s0);
        liftPkH<0>(r2 + 16,  t1, s1);
        liftPkH<1>(r2 + 16,  t2, s2);
        liftPkH<2>(r2 + 16,  t3, s3);
        liftPkH<3>(r2 + 16,  t4, s4);
        liftPk<4>(r2, rlane(tt, 5), rlane(ss, 5));   // q5: cross-half pairs
    }

    transpose64(r2, lds, l);                 // scalar bit k = qubit 6+k

    // ---- pass 2: qubits 6-11, layer 1 ----
    liftIntra (r2, rlane(tt, 6),  rlane(ss, 6));
    liftPk<0>(r2, rlane(tt, 7),  rlane(ss, 7));
    liftPk<1>(r2, rlane(tt, 8),  rlane(ss, 8));
    liftPk<2>(r2, rlane(tt, 9),  rlane(ss, 9));
    liftPk<3>(r2, rlane(tt, 10), rlane(ss, 10));
    liftPk<4>(r2, rlane(tt, 11), rlane(ss, 11));

    // CZ diagonal as sign-bit XOR (verified R10).
    {
        const int l0 = l & 1, l5 = (l >> 5) & 1;
        const int base = __popc(l & (l >> 1) & 0x1F) & 1;  // pairs among qubits 0-5
        uint32_t U[4];
        U[0] = (uint32_t)base << 31;
        U[1] = (uint32_t)(base ^ l5) << 31;            // e0=1: pair (5,6)
        U[2] = (uint32_t)(base ^ l0) << 31;            // e5=1: pair (0,11)
        U[3] = (uint32_t)(base ^ l5 ^ l0) << 31;
#pragma unroll
        for (int e = 0; e < 64; ++e) {
            const int Ce  = __popc(e & (e >> 1) & 0x1F) & 1;  // pairs among 6-11
            const int sel = (e & 1) | (((e >> 5) & 1) << 1);
            const uint32_t msk = U[sel] ^ (Ce ? 0x80000000u : 0u);
            if (e & 1) r2[e >> 1].y = __uint_as_float(__float_as_uint(r2[e >> 1].y) ^ msk);
            else       r2[e >> 1].x = __uint_as_float(__float_as_uint(r2[e >> 1].x) ^ msk);
        }
    }

    // ---- layer 2 on qubits 6-9 (theta[18..21]). q10,q11 gates DROPPED:
    //      a tensor-factor unitary on an unmeasured qubit cannot change the
    //      marginals of q0-q9 (partial-trace invariance; exact).
    liftIntra (r2, rlane(tt, 18), rlane(ss, 18));
    liftPk<0>(r2, rlane(tt, 19), rlane(ss, 19));
    liftPk<1>(r2, rlane(tt, 20), rlane(ss, 20));
    liftPk<2>(r2, rlane(tt, 21), rlane(ss, 21));

    transpose64(r2, lds, l);                 // scalar bit k = qubit k

    // ---- pass 3: qubits 0-5, layer 2 (theta[12..17]) ----
    liftIntra (r2, rlane(tt, 12), rlane(ss, 12));
    liftPk<0>(r2, rlane(tt, 13), rlane(ss, 13));
    liftPk<1>(r2, rlane(tt, 14), rlane(ss, 14));
    liftPk<2>(r2, rlane(tt, 15), rlane(ss, 15));
    liftPk<3>(r2, rlane(tt, 16), rlane(ss, 16));
    liftPk<4>(r2, rlane(tt, 17), rlane(ss, 17));

    // ---- measurement (tree verified R7/R8): d = l*64 + j; qubit k<6 =
    //      j-bit k, qubits 6-9 = lane bits 0-3. Square (pk), halving tree.
#pragma unroll
    for (int m = 0; m < 32; ++m) r2[m] *= r2[m];

    float v0 = 0.f, v1 = 0.f, v2 = 0.f, v3 = 0.f, v4 = 0.f;
    float q32[32];
#pragma unroll
    for (int m = 0; m < 32; ++m) { v0 += r2[m].y; q32[m] = r2[m].x + r2[m].y; }
    float q16[16];
#pragma unroll
    for (int m = 0; m < 16; ++m) { v1 += q32[2*m+1]; q16[m] = q32[2*m] + q32[2*m+1]; }
    float q8[8];
#pragma unroll
    for (int m = 0; m < 8; ++m)  { v2 += q16[2*m+1]; q8[m] = q16[2*m] + q16[2*m+1]; }
    float q4[4];
#pragma unroll
    for (int m = 0; m < 4; ++m)  { v3 += q8[2*m+1]; q4[m] = q8[2*m] + q8[2*m+1]; }
    float q2[2];
#pragma unroll
    for (int m = 0; m < 2; ++m)  { v4 += q4[2*m+1]; q2[m] = q4[2*m] + q4[2*m+1]; }
    const float v5   = q2[1];
    const float psum = q2[0] + q2[1];

    float v[10];
    v[0] = v0; v[1] = v1; v[2] = v2; v[3] = v3; v[4] = v4; v[5] = v5;
    v[6] = (l & 1) ? psum : 0.f;
    v[7] = (l & 2) ? psum : 0.f;
    v[8] = (l & 4) ? psum : 0.f;
    v[9] = (l & 8) ? psum : 0.f;

    // ---- DPP wave reduction (VALU-only; totals land in lane 63) ----
#pragma unroll
    for (int k = 0; k < KOUT; ++k)
        v[k] = dppSum64(v[k]);

    if (l == 63) {
#pragma unroll
        for (int k = 0; k < KOUT; ++k) out[b * KOUT + k] = v[k];
    }
}

extern "C" void kernel_launch(void* const* d_in, const int* in_sizes, int n_in,
                              void* d_out, int out_size, void* d_ws, size_t ws_size,
                              hipStream_t stream) {
    const float* x     = (const float*)d_in[0];
    const float* theta = (const float*)d_in[1];
    float* out         = (float*)d_out;
    vqc_kernel<<<BATCH, 64, 0, stream>>>(x, theta, out);
}

// Round 14
// 25.241 us; speedup vs baseline: 1.7988x; 1.0125x over previous
//
#include <hip/hip_runtime.h>
#include <math.h>
#include <stdint.h>

#define DIM  4096
#define KOUT 10
#define BATCH 4096

typedef float float2v __attribute__((ext_vector_type(2)));

// XOR-swizzle on linear LDS float index (verified R1/R4/R6/R8).
__device__ __forceinline__ int swzAddr(int lin) {
    return lin ^ (((lin >> 6) & 7) << 2);
}

__device__ __forceinline__ float rlane(float v, int lane) {
    return __int_as_float(__builtin_amdgcn_readlane(__float_as_int(v), lane));
}

// Drain all pending LDS ops (necessity verified R6): protects the
// phase-0-read -> phase-1-write WAR inside the time-shared transpose.
__device__ __forceinline__ void ldsFence() {
    __builtin_amdgcn_sched_barrier(0);
    asm volatile("s_waitcnt lgkmcnt(0)" ::: "memory");
    __builtin_amdgcn_sched_barrier(0);
}

// Wave64 sum of 10 values via DPP, interleaved (verified semantics R13).
// gfx9 DPP hazard (VALU write -> DPP read needs 2 wait states; compiler
// does not fence inline asm): entry covered by one s_nop 1; within the
// block, dependent DPPs on the same value are 10 instructions apart.
__device__ __forceinline__ void dppSum64x10(float v[10]) {
#define STAGE(mod) \
    "v_add_f32_dpp %0, %0, %0 " mod "\n\t" \
    "v_add_f32_dpp %1, %1, %1 " mod "\n\t" \
    "v_add_f32_dpp %2, %2, %2 " mod "\n\t" \
    "v_add_f32_dpp %3, %3, %3 " mod "\n\t" \
    "v_add_f32_dpp %4, %4, %4 " mod "\n\t" \
    "v_add_f32_dpp %5, %5, %5 " mod "\n\t" \
    "v_add_f32_dpp %6, %6, %6 " mod "\n\t" \
    "v_add_f32_dpp %7, %7, %7 " mod "\n\t" \
    "v_add_f32_dpp %8, %8, %8 " mod "\n\t" \
    "v_add_f32_dpp %9, %9, %9 " mod "\n\t"
    asm volatile(
        "s_nop 1\n\t"
        STAGE("row_shr:1  row_mask:0xf bank_mask:0xf bound_ctrl:0")
        STAGE("row_shr:2  row_mask:0xf bank_mask:0xf bound_ctrl:0")
        STAGE("row_shr:4  row_mask:0xf bank_mask:0xf bound_ctrl:0")
        STAGE("row_shr:8  row_mask:0xf bank_mask:0xf bound_ctrl:0")
        STAGE("row_bcast:15 row_mask:0xf bank_mask:0xf bound_ctrl:0")
        STAGE("row_bcast:31 row_mask:0xf bank_mask:0xf bound_ctrl:0")
        : "+v"(v[0]), "+v"(v[1]), "+v"(v[2]), "+v"(v[3]), "+v"(v[4]),
          "+v"(v[5]), "+v"(v[6]), "+v"(v[7]), "+v"(v[8]), "+v"(v[9]));
#undef STAGE
    // lane 63 holds each total
}

// Packed RY lifting layer on scalar state bit KP+1 (verified R8).
// t = tan(phi/2), s = sin(phi) (or -cot/-sin => -R; sign cancels in probs).
template<int KP>
__device__ __forceinline__ void liftPk(float2v r2[32], float t, float s) {
    const float2v tv = { -t, -t };
    const float2v sv = {  s,  s };
#pragma unroll
    for (int m = 0; m < 16; ++m) {
        const int i0 = ((m >> KP) << (KP + 1)) | (m & ((1 << KP) - 1));
        const int i1 = i0 | (1 << KP);
        float2v a = r2[i0], b = r2[i1];
        float2v a1 = __builtin_elementwise_fma(tv, b, a);
        float2v b1 = __builtin_elementwise_fma(sv, a1, b);
        r2[i1] = b1;
        r2[i0] = __builtin_elementwise_fma(tv, b1, a1);
    }
}

// Half-array variants (verified R10): state bits 1..4 stay within a half.
template<int KP>
__device__ __forceinline__ void liftPkH(float2v* h, float t, float s) {
    const float2v tv = { -t, -t };
    const float2v sv = {  s,  s };
#pragma unroll
    for (int m = 0; m < 8; ++m) {
        const int i0 = ((m >> KP) << (KP + 1)) | (m & ((1 << KP) - 1));
        const int i1 = i0 | (1 << KP);
        float2v a = h[i0], b = h[i1];
        float2v a1 = __builtin_elementwise_fma(tv, b, a);
        float2v b1 = __builtin_elementwise_fma(sv, a1, b);
        h[i1] = b1;
        h[i0] = __builtin_elementwise_fma(tv, b1, a1);
    }
}

__device__ __forceinline__ void liftIntraH(float2v* h, float t, float s) {
#pragma unroll
    for (int m = 0; m < 16; ++m) {
        float a = h[m].x, b = h[m].y;
        float a1 = fmaf(-t, b, a);
        float b1 = fmaf(s, a1, b);
        h[m].x = fmaf(-t, b1, a1);
        h[m].y = b1;
    }
}

// Full-array scalar layer on state bit 0 (verified R8).
__device__ __forceinline__ void liftIntra(float2v r2[32], float t, float s) {
#pragma unroll
    for (int m = 0; m < 32; ++m) {
        float a = r2[m].x, b = r2[m].y;
        float a1 = fmaf(-t, b, a);
        float b1 = fmaf(s, a1, b);
        r2[m].x = fmaf(-t, b1, a1);
        r2[m].y = b1;
    }
}

// 8 KB time-shared lane<->reg transpose, single middle fence (verified R10).
// Scalar semantics (verified R6/R8): r_new[j]@lane l = r_old[l]@lane j.
__device__ __forceinline__ void transpose64(float2v r2[32], float* lds, int l) {
    float tmp[32];
    if (l < 32) {
#pragma unroll
        for (int e4 = 0; e4 < 16; ++e4)
            *reinterpret_cast<float4*>(&lds[swzAddr(l * 64 + e4 * 4)]) =
                make_float4(r2[2 * e4].x, r2[2 * e4].y,
                            r2[2 * e4 + 1].x, r2[2 * e4 + 1].y);
    }
#pragma unroll
    for (int j = 0; j < 32; ++j)
        tmp[j] = lds[swzAddr(j * 64 + l)];          // new scalars 0..31
    ldsFence();                 // WAR: phase-0 reads must land before overwrite
    if (l >= 32) {
#pragma unroll
        for (int e4 = 0; e4 < 16; ++e4)
            *reinterpret_cast<float4*>(&lds[swzAddr((l - 32) * 64 + e4 * 4)]) =
                make_float4(r2[2 * e4].x, r2[2 * e4].y,
                            r2[2 * e4 + 1].x, r2[2 * e4 + 1].y);
    }
#pragma unroll
    for (int m = 0; m < 16; ++m) {                  // new scalars 32..63
        float2v w;
        w.x = lds[swzAddr((2 * m) * 64 + l)];
        w.y = lds[swzAddr((2 * m + 1) * 64 + l)];
        r2[16 + m] = w;
    }
#pragma unroll
    for (int m = 0; m < 16; ++m) {
        float2v w; w.x = tmp[2 * m]; w.y = tmp[2 * m + 1];
        r2[m] = w;
    }
}

__global__ __launch_bounds__(64) void vqc_kernel(
        const float* __restrict__ x,
        const float* __restrict__ theta,
        float* __restrict__ out)
{
    __shared__ __align__(16) float lds[2048];   // 8 KB
    const int l = threadIdx.x;   // one wave per block, one batch row per block
    const int b = blockIdx.x;

    // Gate params for lifting. RY(theta) rotates by phi = theta/2:
    // t = tan(theta/4), s = sin(theta/2); alt branch -R(phi) keeps |t|<=1.
    // HW trig (v_sin/v_cos): angle error ~1e-6, invisible vs 0.0039 floor.
    float th = theta[l < 24 ? l : 0];
    float qh = 0.25f * th;
    float sq = __sinf(qh), cq = __cosf(qh);
    float sfull = 2.f * sq * cq;                       // sin(theta/2)
    float tt, ss;
    if (fabsf(sq) <= fabsf(cq)) { tt = __fdividef(sq, cq);  ss = sfull;  }
    else                        { tt = -__fdividef(cq, sq); ss = -sfull; }

    // ---- issue all 16 global loads, then compute halves as data arrives ----
    float2v r2[32];
    const float4* x4 = reinterpret_cast<const float4*>(x + (size_t)b * DIM + l * 64);
#pragma unroll
    for (int e4 = 0; e4 < 16; ++e4) {
        const float4 w = x4[e4];
        float2v lo; lo.x = w.x; lo.y = w.y;
        float2v hi; hi.x = w.z; hi.y = w.w;
        r2[2 * e4]     = lo;
        r2[2 * e4 + 1] = hi;
    }

    // ---- pass 1: qubits 0-5, layer 1 (half-split for load overlap, R10) ----
    {
        const float t0 = rlane(tt, 0), s0 = rlane(ss, 0);
        const float t1 = rlane(tt, 1), s1 = rlane(ss, 1);
        const float t2 = rlane(tt, 2), s2 = rlane(ss, 2);
        const float t3 = rlane(tt, 3), s3 = rlane(ss, 3);
        const float t4 = rlane(tt, 4), s4 = rlane(ss, 4);
        liftIntraH (r2,      t0, s0);
        liftPkH<0>(r2,       t1, s1);
        liftPkH<1>(r2,       t2, s2);
        liftPkH<2>(r2,       t3, s3);
        liftPkH<3>(r2,       t4, s4);
        liftIntraH (r2 + 16, t0, s0);
        liftPkH<0>(r2 + 16,  t1, s1);
        liftPkH<1>(r2 + 16,  t2, s2);
        liftPkH<2>(r2 + 16,  t3, s3);
        liftPkH<3>(r2 + 16,  t4, s4);
        liftPk<4>(r2, rlane(tt, 5), rlane(ss, 5));   // q5: cross-half pairs
    }

    transpose64(r2, lds, l);                 // scalar bit k = qubit 6+k

    // ---- pass 2: qubits 6-11, layer 1 ----
    liftIntra (r2, rlane(tt, 6),  rlane(ss, 6));
    liftPk<0>(r2, rlane(tt, 7),  rlane(ss, 7));
    liftPk<1>(r2, rlane(tt, 8),  rlane(ss, 8));
    liftPk<2>(r2, rlane(tt, 9),  rlane(ss, 9));
    liftPk<3>(r2, rlane(tt, 10), rlane(ss, 10));
    liftPk<4>(r2, rlane(tt, 11), rlane(ss, 11));

    // CZ diagonal as sign-bit XOR (verified R10).
    {
        const int l0 = l & 1, l5 = (l >> 5) & 1;
        const int base = __popc(l & (l >> 1) & 0x1F) & 1;  // pairs among qubits 0-5
        uint32_t U[4];
        U[0] = (uint32_t)base << 31;
        U[1] = (uint32_t)(base ^ l5) << 31;            // e0=1: pair (5,6)
        U[2] = (uint32_t)(base ^ l0) << 31;            // e5=1: pair (0,11)
        U[3] = (uint32_t)(base ^ l5 ^ l0) << 31;
#pragma unroll
        for (int e = 0; e < 64; ++e) {
            const int Ce  = __popc(e & (e >> 1) & 0x1F) & 1;  // pairs among 6-11
            const int sel = (e & 1) | (((e >> 5) & 1) << 1);
            const uint32_t msk = U[sel] ^ (Ce ? 0x80000000u : 0u);
            if (e & 1) r2[e >> 1].y = __uint_as_float(__float_as_uint(r2[e >> 1].y) ^ msk);
            else       r2[e >> 1].x = __uint_as_float(__float_as_uint(r2[e >> 1].x) ^ msk);
        }
    }

    // ---- layer 2 on qubits 6-9 (theta[18..21]). q10,q11 gates DROPPED:
    //      partial-trace invariance (verified R13; exact).
    liftIntra (r2, rlane(tt, 18), rlane(ss, 18));
    liftPk<0>(r2, rlane(tt, 19), rlane(ss, 19));
    liftPk<1>(r2, rlane(tt, 20), rlane(ss, 20));
    liftPk<2>(r2, rlane(tt, 21), rlane(ss, 21));

    transpose64(r2, lds, l);                 // scalar bit k = qubit k

    // ---- pass 3: qubits 0-5, layer 2 (theta[12..17]) ----
    liftIntra (r2, rlane(tt, 12), rlane(ss, 12));
    liftPk<0>(r2, rlane(tt, 13), rlane(ss, 13));
    liftPk<1>(r2, rlane(tt, 14), rlane(ss, 14));
    liftPk<2>(r2, rlane(tt, 15), rlane(ss, 15));
    liftPk<3>(r2, rlane(tt, 16), rlane(ss, 16));
    liftPk<4>(r2, rlane(tt, 17), rlane(ss, 17));

    // ---- measurement, packed tree. d = l*64 + j; q0 = j bit 0 (component),
    //      q1-5 = j bits 1-5 (pack index m bits 0-4), q6-9 = lane bits 0-3.
    //      Squares then in-place pk halving tree; odd-index partial sums U_k
    //      give each m-bit marginal; totals give v0 (.y) and psum for free.
#pragma unroll
    for (int m = 0; m < 32; ++m) r2[m] *= r2[m];

    float2v U1 = r2[1];
#pragma unroll
    for (int m = 1; m < 16; ++m) U1 += r2[2 * m + 1];
#pragma unroll
    for (int m = 0; m < 16; ++m) r2[m] = r2[2 * m] + r2[2 * m + 1];   // T1

    float2v U2 = r2[1];
#pragma unroll
    for (int m = 1; m < 8; ++m) U2 += r2[2 * m + 1];
#pragma unroll
    for (int m = 0; m < 8; ++m) r2[m] = r2[2 * m] + r2[2 * m + 1];    // T2

    const float2v U3 = (r2[1] + r2[3]) + (r2[5] + r2[7]);
#pragma unroll
    for (int m = 0; m < 4; ++m) r2[m] = r2[2 * m] + r2[2 * m + 1];    // T3

    const float2v U4  = r2[1] + r2[3];
    const float2v T4a = r2[0] + r2[1];
    const float2v T4b = r2[2] + r2[3];
    const float2v Tot = T4a + T4b;
    const float psum  = Tot.x + Tot.y;

    float v[10];
    v[0] = Tot.y;
    v[1] = U1.x + U1.y;
    v[2] = U2.x + U2.y;
    v[3] = U3.x + U3.y;
    v[4] = U4.x + U4.y;
    v[5] = T4b.x + T4b.y;
    v[6] = (l & 1) ? psum : 0.f;
    v[7] = (l & 2) ? psum : 0.f;
    v[8] = (l & 4) ? psum : 0.f;
    v[9] = (l & 8) ? psum : 0.f;

    // ---- interleaved DPP wave reduction (VALU-only; totals in lane 63) ----
    dppSum64x10(v);

    if (l == 63) {
#pragma unroll
        for (int k = 0; k < KOUT; ++k) out[b * KOUT + k] = v[k];
    }
}

extern "C" void kernel_launch(void* const* d_in, const int* in_sizes, int n_in,
                              void* d_out, int out_size, void* d_ws, size_t ws_size,
                              hipStream_t stream) {
    const float* x     = (const float*)d_in[0];
    const float* theta = (const float*)d_in[1];
    float* out         = (float*)d_out;
    vqc_kernel<<<BATCH, 64, 0, stream>>>(x, theta, out);
}

// Round 15
// 24.835 us; speedup vs baseline: 1.8282x; 1.0164x over previous
//
#include <hip/hip_runtime.h>
#include <math.h>
#include <stdint.h>

#define DIM  4096
#define KOUT 10
#define BATCH 4096

typedef float float2v __attribute__((ext_vector_type(2)));

// ROW-PAIR XOR-swizzle on linear LDS float index: XOR row-pair bits (7-9)
// into 16B-granule slot bits (2-4). Involution. Rows 2m and 2m+1 share the
// same lane-XOR, so column reads of a row pair are exactly 64 dwords apart
// -> compiler merges them into ds_read2_b32 offset1:64 (one issue slot).
// Bank patterns: b128 row writes 4 lanes/bank-quad (empirically-free level,
// same as R1-R14's row-swizzle); b32/read2 column reads exact 2-way (free).
__device__ __forceinline__ int swzAddr(int lin) {
    return lin ^ (((lin >> 7) & 7) << 2);
}

__device__ __forceinline__ float rlane(float v, int lane) {
    return __int_as_float(__builtin_amdgcn_readlane(__float_as_int(v), lane));
}

// Drain all pending LDS ops (necessity verified R6): protects the
// phase-0-read -> phase-1-write WAR inside the time-shared transpose.
__device__ __forceinline__ void ldsFence() {
    __builtin_amdgcn_sched_barrier(0);
    asm volatile("s_waitcnt lgkmcnt(0)" ::: "memory");
    __builtin_amdgcn_sched_barrier(0);
}

// Wave64 sum of 10 values via DPP, interleaved (verified R13/R14).
// gfx9 DPP hazard (VALU write -> DPP read needs 2 wait states; compiler
// does not fence inline asm): entry covered by one s_nop 1; within the
// block, dependent DPPs on the same value are 10 instructions apart.
__device__ __forceinline__ void dppSum64x10(float v[10]) {
#define STAGE(mod) \
    "v_add_f32_dpp %0, %0, %0 " mod "\n\t" \
    "v_add_f32_dpp %1, %1, %1 " mod "\n\t" \
    "v_add_f32_dpp %2, %2, %2 " mod "\n\t" \
    "v_add_f32_dpp %3, %3, %3 " mod "\n\t" \
    "v_add_f32_dpp %4, %4, %4 " mod "\n\t" \
    "v_add_f32_dpp %5, %5, %5 " mod "\n\t" \
    "v_add_f32_dpp %6, %6, %6 " mod "\n\t" \
    "v_add_f32_dpp %7, %7, %7 " mod "\n\t" \
    "v_add_f32_dpp %8, %8, %8 " mod "\n\t" \
    "v_add_f32_dpp %9, %9, %9 " mod "\n\t"
    asm volatile(
        "s_nop 1\n\t"
        STAGE("row_shr:1  row_mask:0xf bank_mask:0xf bound_ctrl:0")
        STAGE("row_shr:2  row_mask:0xf bank_mask:0xf bound_ctrl:0")
        STAGE("row_shr:4  row_mask:0xf bank_mask:0xf bound_ctrl:0")
        STAGE("row_shr:8  row_mask:0xf bank_mask:0xf bound_ctrl:0")
        STAGE("row_bcast:15 row_mask:0xf bank_mask:0xf bound_ctrl:0")
        STAGE("row_bcast:31 row_mask:0xf bank_mask:0xf bound_ctrl:0")
        : "+v"(v[0]), "+v"(v[1]), "+v"(v[2]), "+v"(v[3]), "+v"(v[4]),
          "+v"(v[5]), "+v"(v[6]), "+v"(v[7]), "+v"(v[8]), "+v"(v[9]));
#undef STAGE
    // lane 63 holds each total
}

// Packed RY lifting layer on scalar state bit KP+1 (verified R8).
// t = tan(phi/2), s = sin(phi) (or -cot/-sin => -R; sign cancels in probs).
template<int KP>
__device__ __forceinline__ void liftPk(float2v r2[32], float t, float s) {
    const float2v tv = { -t, -t };
    const float2v sv = {  s,  s };
#pragma unroll
    for (int m = 0; m < 16; ++m) {
        const int i0 = ((m >> KP) << (KP + 1)) | (m & ((1 << KP) - 1));
        const int i1 = i0 | (1 << KP);
        float2v a = r2[i0], b = r2[i1];
        float2v a1 = __builtin_elementwise_fma(tv, b, a);
        float2v b1 = __builtin_elementwise_fma(sv, a1, b);
        r2[i1] = b1;
        r2[i0] = __builtin_elementwise_fma(tv, b1, a1);
    }
}

// Half-array variants (verified R10): state bits 1..4 stay within a half.
template<int KP>
__device__ __forceinline__ void liftPkH(float2v* h, float t, float s) {
    const float2v tv = { -t, -t };
    const float2v sv = {  s,  s };
#pragma unroll
    for (int m = 0; m < 8; ++m) {
        const int i0 = ((m >> KP) << (KP + 1)) | (m & ((1 << KP) - 1));
        const int i1 = i0 | (1 << KP);
        float2v a = h[i0], b = h[i1];
        float2v a1 = __builtin_elementwise_fma(tv, b, a);
        float2v b1 = __builtin_elementwise_fma(sv, a1, b);
        h[i1] = b1;
        h[i0] = __builtin_elementwise_fma(tv, b1, a1);
    }
}

__device__ __forceinline__ void liftIntraH(float2v* h, float t, float s) {
#pragma unroll
    for (int m = 0; m < 16; ++m) {
        float a = h[m].x, b = h[m].y;
        float a1 = fmaf(-t, b, a);
        float b1 = fmaf(s, a1, b);
        h[m].x = fmaf(-t, b1, a1);
        h[m].y = b1;
    }
}

// Full-array scalar layer on state bit 0 (verified R8).
__device__ __forceinline__ void liftIntra(float2v r2[32], float t, float s) {
#pragma unroll
    for (int m = 0; m < 32; ++m) {
        float a = r2[m].x, b = r2[m].y;
        float a1 = fmaf(-t, b, a);
        float b1 = fmaf(s, a1, b);
        r2[m].x = fmaf(-t, b1, a1);
        r2[m].y = b1;
    }
}

// 8 KB time-shared lane<->reg transpose, single middle fence (verified R10),
// with row-pair-swizzled column reads merged into ds_read2_b32.
// Scalar semantics (verified R6/R8): r_new[j]@lane l = r_old[l]@lane j.
__device__ __forceinline__ void transpose64(float2v r2[32], float* lds, int l) {
    float tmp[32];
    if (l < 32) {
#pragma unroll
        for (int e4 = 0; e4 < 16; ++e4)
            *reinterpret_cast<float4*>(&lds[swzAddr(l * 64 + e4 * 4)]) =
                make_float4(r2[2 * e4].x, r2[2 * e4].y,
                            r2[2 * e4 + 1].x, r2[2 * e4 + 1].y);
    }
#pragma unroll
    for (int m = 0; m < 16; ++m) {                  // new scalars 0..31
        const int base = swzAddr((2 * m) * 64 + l); // rows 2m,2m+1 share xor
        tmp[2 * m]     = lds[base];
        tmp[2 * m + 1] = lds[base + 64];            // -> ds_read2_b32
    }
    ldsFence();                 // WAR: phase-0 reads must land before overwrite
    if (l >= 32) {
#pragma unroll
        for (int e4 = 0; e4 < 16; ++e4)
            *reinterpret_cast<float4*>(&lds[swzAddr((l - 32) * 64 + e4 * 4)]) =
                make_float4(r2[2 * e4].x, r2[2 * e4].y,
                            r2[2 * e4 + 1].x, r2[2 * e4 + 1].y);
    }
#pragma unroll
    for (int m = 0; m < 16; ++m) {                  // new scalars 32..63
        const int base = swzAddr((2 * m) * 64 + l);
        float2v w;
        w.x = lds[base];
        w.y = lds[base + 64];                       // -> ds_read2_b32
        r2[16 + m] = w;
    }
#pragma unroll
    for (int m = 0; m < 16; ++m) {
        float2v w; w.x = tmp[2 * m]; w.y = tmp[2 * m + 1];
        r2[m] = w;
    }
}

__global__ __launch_bounds__(64) void vqc_kernel(
        const float* __restrict__ x,
        const float* __restrict__ theta,
        float* __restrict__ out)
{
    __shared__ __align__(16) float lds[2048];   // 8 KB
    const int l = threadIdx.x;   // one wave per block, one batch row per block
    const int b = blockIdx.x;

    // Gate params for lifting. RY(theta) rotates by phi = theta/2:
    // t = tan(theta/4), s = sin(theta/2); alt branch -R(phi) keeps |t|<=1.
    // HW trig (v_sin/v_cos): angle error ~1e-6, invisible vs 0.0039 floor.
    float th = theta[l < 24 ? l : 0];
    float qh = 0.25f * th;
    float sq = __sinf(qh), cq = __cosf(qh);
    float sfull = 2.f * sq * cq;                       // sin(theta/2)
    float tt, ss;
    if (fabsf(sq) <= fabsf(cq)) { tt = __fdividef(sq, cq);  ss = sfull;  }
    else                        { tt = -__fdividef(cq, sq); ss = -sfull; }

    // ---- issue all 16 global loads, then compute halves as data arrives ----
    float2v r2[32];
    const float4* x4 = reinterpret_cast<const float4*>(x + (size_t)b * DIM + l * 64);
#pragma unroll
    for (int e4 = 0; e4 < 16; ++e4) {
        const float4 w = x4[e4];
        float2v lo; lo.x = w.x; lo.y = w.y;
        float2v hi; hi.x = w.z; hi.y = w.w;
        r2[2 * e4]     = lo;
        r2[2 * e4 + 1] = hi;
    }

    // ---- pass 1: qubits 0-5, layer 1 (half-split for load overlap, R10) ----
    {
        const float t0 = rlane(tt, 0), s0 = rlane(ss, 0);
        const float t1 = rlane(tt, 1), s1 = rlane(ss, 1);
        const float t2 = rlane(tt, 2), s2 = rlane(ss, 2);
        const float t3 = rlane(tt, 3), s3 = rlane(ss, 3);
        const float t4 = rlane(tt, 4), s4 = rlane(ss, 4);
        liftIntraH (r2,      t0, s0);
        liftPkH<0>(r2,       t1, s1);
        liftPkH<1>(r2,       t2, s2);
        liftPkH<2>(r2,       t3, s3);
        liftPkH<3>(r2,       t4, s4);
        liftIntraH (r2 + 16, t0, s0);
        liftPkH<0>(r2 + 16,  t1, s1);
        liftPkH<1>(r2 + 16,  t2, s2);
        liftPkH<2>(r2 + 16,  t3, s3);
        liftPkH<3>(r2 + 16,  t4, s4);
        liftPk<4>(r2, rlane(tt, 5), rlane(ss, 5));   // q5: cross-half pairs
    }

    transpose64(r2, lds, l);                 // scalar bit k = qubit 6+k

    // ---- pass 2: qubits 6-11, layer 1 ----
    liftIntra (r2, rlane(tt, 6),  rlane(ss, 6));
    liftPk<0>(r2, rlane(tt, 7),  rlane(ss, 7));
    liftPk<1>(r2, rlane(tt, 8),  rlane(ss, 8));
    liftPk<2>(r2, rlane(tt, 9),  rlane(ss, 9));
    liftPk<3>(r2, rlane(tt, 10), rlane(ss, 10));
    liftPk<4>(r2, rlane(tt, 11), rlane(ss, 11));

    // CZ diagonal as sign-bit XOR (verified R10).
    {
        const int l0 = l & 1, l5 = (l >> 5) & 1;
        const int base = __popc(l & (l >> 1) & 0x1F) & 1;  // pairs among qubits 0-5
        uint32_t U[4];
        U[0] = (uint32_t)base << 31;
        U[1] = (uint32_t)(base ^ l5) << 31;            // e0=1: pair (5,6)
        U[2] = (uint32_t)(base ^ l0) << 31;            // e5=1: pair (0,11)
        U[3] = (uint32_t)(base ^ l5 ^ l0) << 31;
#pragma unroll
        for (int e = 0; e < 64; ++e) {
            const int Ce  = __popc(e & (e >> 1) & 0x1F) & 1;  // pairs among 6-11
            const int sel = (e & 1) | (((e >> 5) & 1) << 1);
            const uint32_t msk = U[sel] ^ (Ce ? 0x80000000u : 0u);
            if (e & 1) r2[e >> 1].y = __uint_as_float(__float_as_uint(r2[e >> 1].y) ^ msk);
            else       r2[e >> 1].x = __uint_as_float(__float_as_uint(r2[e >> 1].x) ^ msk);
        }
    }

    // ---- layer 2 on qubits 6-9 (theta[18..21]). q10,q11 gates DROPPED:
    //      partial-trace invariance (verified R13; exact).
    liftIntra (r2, rlane(tt, 18), rlane(ss, 18));
    liftPk<0>(r2, rlane(tt, 19), rlane(ss, 19));
    liftPk<1>(r2, rlane(tt, 20), rlane(ss, 20));
    liftPk<2>(r2, rlane(tt, 21), rlane(ss, 21));

    transpose64(r2, lds, l);                 // scalar bit k = qubit k

    // ---- pass 3: qubits 0-5, layer 2 (theta[12..17]) ----
    liftIntra (r2, rlane(tt, 12), rlane(ss, 12));
    liftPk<0>(r2, rlane(tt, 13), rlane(ss, 13));
    liftPk<1>(r2, rlane(tt, 14), rlane(ss, 14));
    liftPk<2>(r2, rlane(tt, 15), rlane(ss, 15));
    liftPk<3>(r2, rlane(tt, 16), rlane(ss, 16));
    liftPk<4>(r2, rlane(tt, 17), rlane(ss, 17));

    // ---- measurement, packed tree (verified R14). d = l*64 + j; q0 = j bit 0
    //      (component), q1-5 = pack index bits 0-4, q6-9 = lane bits 0-3.
#pragma unroll
    for (int m = 0; m < 32; ++m) r2[m] *= r2[m];

    float2v U1 = r2[1];
#pragma unroll
    for (int m = 1; m < 16; ++m) U1 += r2[2 * m + 1];
#pragma unroll
    for (int m = 0; m < 16; ++m) r2[m] = r2[2 * m] + r2[2 * m + 1];   // T1

    float2v U2 = r2[1];
#pragma unroll
    for (int m = 1; m < 8; ++m) U2 += r2[2 * m + 1];
#pragma unroll
    for (int m = 0; m < 8; ++m) r2[m] = r2[2 * m] + r2[2 * m + 1];    // T2

    const float2v U3 = (r2[1] + r2[3]) + (r2[5] + r2[7]);
#pragma unroll
    for (int m = 0; m < 4; ++m) r2[m] = r2[2 * m] + r2[2 * m + 1];    // T3

    const float2v U4  = r2[1] + r2[3];
    const float2v T4a = r2[0] + r2[1];
    const float2v T4b = r2[2] + r2[3];
    const float2v Tot = T4a + T4b;
    const float psum  = Tot.x + Tot.y;

    float v[10];
    v[0] = Tot.y;
    v[1] = U1.x + U1.y;
    v[2] = U2.x + U2.y;
    v[3] = U3.x + U3.y;
    v[4] = U4.x + U4.y;
    v[5] = T4b.x + T4b.y;
    v[6] = (l & 1) ? psum : 0.f;
    v[7] = (l & 2) ? psum : 0.f;
    v[8] = (l & 4) ? psum : 0.f;
    v[9] = (l & 8) ? psum : 0.f;

    // ---- interleaved DPP wave reduction (VALU-only; totals in lane 63) ----
    dppSum64x10(v);

    if (l == 63) {
#pragma unroll
        for (int k = 0; k < KOUT; ++k) out[b * KOUT + k] = v[k];
    }
}

extern "C" void kernel_launch(void* const* d_in, const int* in_sizes, int n_in,
                              void* d_out, int out_size, void* d_ws, size_t ws_size,
                              hipStream_t stream) {
    const float* x     = (const float*)d_in[0];
    const float* theta = (const float*)d_in[1];
    float* out         = (float*)d_out;
    vqc_kernel<<<BATCH, 64, 0, stream>>>(x, theta, out);
}

// Round 16
// 24.788 us; speedup vs baseline: 1.8316x; 1.0019x over previous
//
#include <hip/hip_runtime.h>
#include <math.h>
#include <stdint.h>

#define DIM  4096
#define KOUT 10
#define BATCH 4096

typedef float float2v __attribute__((ext_vector_type(2)));

// ROW-PAIR XOR-swizzle on linear LDS float index (verified R15): XOR
// row-pair bits (7-9) into 16B-granule slot bits (2-4). Involution.
// Rows 2m,2m+1 share the lane-XOR -> column reads pair into ds_read2_b32.
__device__ __forceinline__ int swzAddr(int lin) {
    return lin ^ (((lin >> 7) & 7) << 2);
}

__device__ __forceinline__ float rlane(float v, int lane) {
    return __int_as_float(__builtin_amdgcn_readlane(__float_as_int(v), lane));
}

// COMPILE-TIME ordering fence (R16 experiment): pins the phase-0 reads
// before the phase-1 writes in program order (sched_barrier + memory
// clobber), relying on the DS pipe's same-wave in-order execution for the
// HW side. R5's corruption is attributed to compiler reordering (it had
// neither clobber nor sched_barrier); R6 fixed it with sched_barrier +
// s_waitcnt together — this round separates the two effects.
__device__ __forceinline__ void ldsOrder() {
    __builtin_amdgcn_sched_barrier(0);
    asm volatile("" ::: "memory");
    __builtin_amdgcn_sched_barrier(0);
}

// Wave64 sum of 10 values via DPP, interleaved (verified R13/R14).
// gfx9 DPP hazard (VALU write -> DPP read needs 2 wait states; compiler
// does not fence inline asm): entry covered by one s_nop 1; within the
// block, dependent DPPs on the same value are 10 instructions apart.
__device__ __forceinline__ void dppSum64x10(float v[10]) {
#define STAGE(mod) \
    "v_add_f32_dpp %0, %0, %0 " mod "\n\t" \
    "v_add_f32_dpp %1, %1, %1 " mod "\n\t" \
    "v_add_f32_dpp %2, %2, %2 " mod "\n\t" \
    "v_add_f32_dpp %3, %3, %3 " mod "\n\t" \
    "v_add_f32_dpp %4, %4, %4 " mod "\n\t" \
    "v_add_f32_dpp %5, %5, %5 " mod "\n\t" \
    "v_add_f32_dpp %6, %6, %6 " mod "\n\t" \
    "v_add_f32_dpp %7, %7, %7 " mod "\n\t" \
    "v_add_f32_dpp %8, %8, %8 " mod "\n\t" \
    "v_add_f32_dpp %9, %9, %9 " mod "\n\t"
    asm volatile(
        "s_nop 1\n\t"
        STAGE("row_shr:1  row_mask:0xf bank_mask:0xf bound_ctrl:0")
        STAGE("row_shr:2  row_mask:0xf bank_mask:0xf bound_ctrl:0")
        STAGE("row_shr:4  row_mask:0xf bank_mask:0xf bound_ctrl:0")
        STAGE("row_shr:8  row_mask:0xf bank_mask:0xf bound_ctrl:0")
        STAGE("row_bcast:15 row_mask:0xf bank_mask:0xf bound_ctrl:0")
        STAGE("row_bcast:31 row_mask:0xf bank_mask:0xf bound_ctrl:0")
        : "+v"(v[0]), "+v"(v[1]), "+v"(v[2]), "+v"(v[3]), "+v"(v[4]),
          "+v"(v[5]), "+v"(v[6]), "+v"(v[7]), "+v"(v[8]), "+v"(v[9]));
#undef STAGE
    // lane 63 holds each total
}

// Packed RY lifting layer on scalar state bit KP+1 (verified R8).
// t = tan(phi/2), s = sin(phi) (or -cot/-sin => -R; sign cancels in probs).
template<int KP>
__device__ __forceinline__ void liftPk(float2v r2[32], float t, float s) {
    const float2v tv = { -t, -t };
    const float2v sv = {  s,  s };
#pragma unroll
    for (int m = 0; m < 16; ++m) {
        const int i0 = ((m >> KP) << (KP + 1)) | (m & ((1 << KP) - 1));
        const int i1 = i0 | (1 << KP);
        float2v a = r2[i0], b = r2[i1];
        float2v a1 = __builtin_elementwise_fma(tv, b, a);
        float2v b1 = __builtin_elementwise_fma(sv, a1, b);
        r2[i1] = b1;
        r2[i0] = __builtin_elementwise_fma(tv, b1, a1);
    }
}

// Half-array variants (verified R10): state bits 1..4 stay within a half.
template<int KP>
__device__ __forceinline__ void liftPkH(float2v* h, float t, float s) {
    const float2v tv = { -t, -t };
    const float2v sv = {  s,  s };
#pragma unroll
    for (int m = 0; m < 8; ++m) {
        const int i0 = ((m >> KP) << (KP + 1)) | (m & ((1 << KP) - 1));
        const int i1 = i0 | (1 << KP);
        float2v a = h[i0], b = h[i1];
        float2v a1 = __builtin_elementwise_fma(tv, b, a);
        float2v b1 = __builtin_elementwise_fma(sv, a1, b);
        h[i1] = b1;
        h[i0] = __builtin_elementwise_fma(tv, b1, a1);
    }
}

__device__ __forceinline__ void liftIntraH(float2v* h, float t, float s) {
#pragma unroll
    for (int m = 0; m < 16; ++m) {
        float a = h[m].x, b = h[m].y;
        float a1 = fmaf(-t, b, a);
        float b1 = fmaf(s, a1, b);
        h[m].x = fmaf(-t, b1, a1);
        h[m].y = b1;
    }
}

// Full-array scalar layer on state bit 0 (verified R8).
__device__ __forceinline__ void liftIntra(float2v r2[32], float t, float s) {
#pragma unroll
    for (int m = 0; m < 32; ++m) {
        float a = r2[m].x, b = r2[m].y;
        float a1 = fmaf(-t, b, a);
        float b1 = fmaf(s, a1, b);
        r2[m].x = fmaf(-t, b1, a1);
        r2[m].y = b1;
    }
}

// 8 KB time-shared lane<->reg transpose (verified R10/R15), compile-time
// ordering only (R16). Scalar semantics: r_new[j]@lane l = r_old[l]@lane j.
__device__ __forceinline__ void transpose64(float2v r2[32], float* lds, int l) {
    float tmp[32];
    if (l < 32) {
#pragma unroll
        for (int e4 = 0; e4 < 16; ++e4)
            *reinterpret_cast<float4*>(&lds[swzAddr(l * 64 + e4 * 4)]) =
                make_float4(r2[2 * e4].x, r2[2 * e4].y,
                            r2[2 * e4 + 1].x, r2[2 * e4 + 1].y);
    }
#pragma unroll
    for (int m = 0; m < 16; ++m) {                  // new scalars 0..31
        const int base = swzAddr((2 * m) * 64 + l); // rows 2m,2m+1 share xor
        tmp[2 * m]     = lds[base];
        tmp[2 * m + 1] = lds[base + 64];            // -> ds_read2_b32
    }
    ldsOrder();   // WAR: pin phase-0 reads before phase-1 overwrite (program order)
    if (l >= 32) {
#pragma unroll
        for (int e4 = 0; e4 < 16; ++e4)
            *reinterpret_cast<float4*>(&lds[swzAddr((l - 32) * 64 + e4 * 4)]) =
                make_float4(r2[2 * e4].x, r2[2 * e4].y,
                            r2[2 * e4 + 1].x, r2[2 * e4 + 1].y);
    }
#pragma unroll
    for (int m = 0; m < 16; ++m) {                  // new scalars 32..63
        const int base = swzAddr((2 * m) * 64 + l);
        float2v w;
        w.x = lds[base];
        w.y = lds[base + 64];                       // -> ds_read2_b32
        r2[16 + m] = w;
    }
#pragma unroll
    for (int m = 0; m < 16; ++m) {
        float2v w; w.x = tmp[2 * m]; w.y = tmp[2 * m + 1];
        r2[m] = w;
    }
}

__global__ __launch_bounds__(64) void vqc_kernel(
        const float* __restrict__ x,
        const float* __restrict__ theta,
        float* __restrict__ out)
{
    __shared__ __align__(16) float lds[2048];   // 8 KB
    const int l = threadIdx.x;   // one wave per block, one batch row per block
    const int b = blockIdx.x;

    // Gate params for lifting. RY(theta) rotates by phi = theta/2:
    // t = tan(theta/4), s = sin(theta/2); alt branch -R(phi) keeps |t|<=1.
    // HW trig (v_sin/v_cos): angle error ~1e-6, invisible vs 0.0039 floor.
    float th = theta[l < 24 ? l : 0];
    float qh = 0.25f * th;
    float sq = __sinf(qh), cq = __cosf(qh);
    float sfull = 2.f * sq * cq;                       // sin(theta/2)
    float tt, ss;
    if (fabsf(sq) <= fabsf(cq)) { tt = __fdividef(sq, cq);  ss = sfull;  }
    else                        { tt = -__fdividef(cq, sq); ss = -sfull; }

    // ---- issue all 16 global loads, then compute halves as data arrives ----
    float2v r2[32];
    const float4* x4 = reinterpret_cast<const float4*>(x + (size_t)b * DIM + l * 64);
#pragma unroll
    for (int e4 = 0; e4 < 16; ++e4) {
        const float4 w = x4[e4];
        float2v lo; lo.x = w.x; lo.y = w.y;
        float2v hi; hi.x = w.z; hi.y = w.w;
        r2[2 * e4]     = lo;
        r2[2 * e4 + 1] = hi;
    }

    // ---- pass 1: qubits 0-5, layer 1 (half-split for load overlap, R10) ----
    {
        const float t0 = rlane(tt, 0), s0 = rlane(ss, 0);
        const float t1 = rlane(tt, 1), s1 = rlane(ss, 1);
        const float t2 = rlane(tt, 2), s2 = rlane(ss, 2);
        const float t3 = rlane(tt, 3), s3 = rlane(ss, 3);
        const float t4 = rlane(tt, 4), s4 = rlane(ss, 4);
        liftIntraH (r2,      t0, s0);
        liftPkH<0>(r2,       t1, s1);
        liftPkH<1>(r2,       t2, s2);
        liftPkH<2>(r2,       t3, s3);
        liftPkH<3>(r2,       t4, s4);
        liftIntraH (r2 + 16, t0, s0);
        liftPkH<0>(r2 + 16,  t1, s1);
        liftPkH<1>(r2 + 16,  t2, s2);
        liftPkH<2>(r2 + 16,  t3, s3);
        liftPkH<3>(r2 + 16,  t4, s4);
        liftPk<4>(r2, rlane(tt, 5), rlane(ss, 5));   // q5: cross-half pairs
    }

    transpose64(r2, lds, l);                 // scalar bit k = qubit 6+k

    // ---- pass 2: qubits 6-11, layer 1 ----
    liftIntra (r2, rlane(tt, 6),  rlane(ss, 6));
    liftPk<0>(r2, rlane(tt, 7),  rlane(ss, 7));
    liftPk<1>(r2, rlane(tt, 8),  rlane(ss, 8));
    liftPk<2>(r2, rlane(tt, 9),  rlane(ss, 9));
    liftPk<3>(r2, rlane(tt, 10), rlane(ss, 10));
    liftPk<4>(r2, rlane(tt, 11), rlane(ss, 11));

    // CZ diagonal as sign-bit XOR (verified R10).
    {
        const int l0 = l & 1, l5 = (l >> 5) & 1;
        const int base = __popc(l & (l >> 1) & 0x1F) & 1;  // pairs among qubits 0-5
        uint32_t U[4];
        U[0] = (uint32_t)base << 31;
        U[1] = (uint32_t)(base ^ l5) << 31;            // e0=1: pair (5,6)
        U[2] = (uint32_t)(base ^ l0) << 31;            // e5=1: pair (0,11)
        U[3] = (uint32_t)(base ^ l5 ^ l0) << 31;
#pragma unroll
        for (int e = 0; e < 64; ++e) {
            const int Ce  = __popc(e & (e >> 1) & 0x1F) & 1;  // pairs among 6-11
            const int sel = (e & 1) | (((e >> 5) & 1) << 1);
            const uint32_t msk = U[sel] ^ (Ce ? 0x80000000u : 0u);
            if (e & 1) r2[e >> 1].y = __uint_as_float(__float_as_uint(r2[e >> 1].y) ^ msk);
            else       r2[e >> 1].x = __uint_as_float(__float_as_uint(r2[e >> 1].x) ^ msk);
        }
    }

    // ---- layer 2 on qubits 6-9 (theta[18..21]). q10,q11 gates DROPPED:
    //      partial-trace invariance (verified R13; exact).
    liftIntra (r2, rlane(tt, 18), rlane(ss, 18));
    liftPk<0>(r2, rlane(tt, 19), rlane(ss, 19));
    liftPk<1>(r2, rlane(tt, 20), rlane(ss, 20));
    liftPk<2>(r2, rlane(tt, 21), rlane(ss, 21));

    transpose64(r2, lds, l);                 // scalar bit k = qubit k

    // ---- pass 3: qubits 0-5, layer 2 (theta[12..17]) ----
    liftIntra (r2, rlane(tt, 12), rlane(ss, 12));
    liftPk<0>(r2, rlane(tt, 13), rlane(ss, 13));
    liftPk<1>(r2, rlane(tt, 14), rlane(ss, 14));
    liftPk<2>(r2, rlane(tt, 15), rlane(ss, 15));
    liftPk<3>(r2, rlane(tt, 16), rlane(ss, 16));
    liftPk<4>(r2, rlane(tt, 17), rlane(ss, 17));

    // ---- measurement, packed tree (verified R14). d = l*64 + j; q0 = j bit 0
    //      (component), q1-5 = pack index bits 0-4, q6-9 = lane bits 0-3.
#pragma unroll
    for (int m = 0; m < 32; ++m) r2[m] *= r2[m];

    float2v U1 = r2[1];
#pragma unroll
    for (int m = 1; m < 16; ++m) U1 += r2[2 * m + 1];
#pragma unroll
    for (int m = 0; m < 16; ++m) r2[m] = r2[2 * m] + r2[2 * m + 1];   // T1

    float2v U2 = r2[1];
#pragma unroll
    for (int m = 1; m < 8; ++m) U2 += r2[2 * m + 1];
#pragma unroll
    for (int m = 0; m < 8; ++m) r2[m] = r2[2 * m] + r2[2 * m + 1];    // T2

    const float2v U3 = (r2[1] + r2[3]) + (r2[5] + r2[7]);
#pragma unroll
    for (int m = 0; m < 4; ++m) r2[m] = r2[2 * m] + r2[2 * m + 1];    // T3

    const float2v U4  = r2[1] + r2[3];
    const float2v T4a = r2[0] + r2[1];
    const float2v T4b = r2[2] + r2[3];
    const float2v Tot = T4a + T4b;
    const float psum  = Tot.x + Tot.y;

    float v[10];
    v[0] = Tot.y;
    v[1] = U1.x + U1.y;
    v[2] = U2.x + U2.y;
    v[3] = U3.x + U3.y;
    v[4] = U4.x + U4.y;
    v[5] = T4b.x + T4b.y;
    v[6] = (l & 1) ? psum : 0.f;
    v[7] = (l & 2) ? psum : 0.f;
    v[8] = (l & 4) ? psum : 0.f;
    v[9] = (l & 8) ? psum : 0.f;

    // ---- interleaved DPP wave reduction (VALU-only; totals in lane 63) ----
    dppSum64x10(v);

    if (l == 63) {
#pragma unroll
        for (int k = 0; k < KOUT; ++k) out[b * KOUT + k] = v[k];
    }
}

extern "C" void kernel_launch(void* const* d_in, const int* in_sizes, int n_in,
                              void* d_out, int out_size, void* d_ws, size_t ws_size,
                              hipStream_t stream) {
    const float* x     = (const float*)d_in[0];
    const float* theta = (const float*)d_in[1];
    float* out         = (float*)d_out;
    vqc_kernel<<<BATCH, 64, 0, stream>>>(x, theta, out);
}